// Round 11
// baseline (680.321 us; speedup 1.0000x reference)
//
#include <hip/hip_runtime.h>
#include <math.h>

#define B_   128
#define L_   197
#define C_   768
#define Nv_  196
#define Lt_  32
#define Ct_  512
#define H_   12
#define DH_  64
#define DPP_ 256
#define MTOK 25088   // B_*Nv_

typedef __attribute__((ext_vector_type(8))) short bf16x8_t;
typedef __attribute__((ext_vector_type(4))) float f32x4_t;

// split fp32 -> bf16 hi (truncate) + bf16 lo (RNE of remainder)
__device__ __forceinline__ void split_bf16(float a, unsigned &h, unsigned &l) {
    unsigned u = __float_as_uint(a);
    unsigned hu = u & 0xffff0000u;
    h = hu >> 16;
    float lf = a - __uint_as_float(hu);
    unsigned ul = __float_as_uint(lf);
    l = (ul + 0x7fffu + ((ul >> 16) & 1u)) >> 16;
}

__device__ __forceinline__ void split8_pack(const float* av, uint4& Hh, uint4& Ll) {
    unsigned hv[8], lv[8];
#pragma unroll
    for (int j = 0; j < 8; ++j) split_bf16(av[j], hv[j], lv[j]);
    Hh.x = hv[0] | (hv[1] << 16); Hh.y = hv[2] | (hv[3] << 16);
    Hh.z = hv[4] | (hv[5] << 16); Hh.w = hv[6] | (hv[7] << 16);
    Ll.x = lv[0] | (lv[1] << 16); Ll.y = lv[2] | (lv[3] << 16);
    Ll.z = lv[4] | (lv[5] << 16); Ll.w = lv[6] | (lv[7] << 16);
}

// ---------------------------------------------------------------------------
// fused weight pre-split (all 5 weights in one launch) — r9-verified
// ---------------------------------------------------------------------------
#define NWQ 589824
#define NWK 393216
#define NWD 196608
__global__ __launch_bounds__(256)
void split_all(const float* __restrict__ Wq, const float* __restrict__ W1,
               const float* __restrict__ Wk, const float* __restrict__ Wv,
               const float* __restrict__ Wd,
               short* __restrict__ Wq_h, short* __restrict__ Wq_l,
               short* __restrict__ W1_h, short* __restrict__ W1_l,
               short* __restrict__ Wk_h, short* __restrict__ Wk_l,
               short* __restrict__ Wv_h, short* __restrict__ Wv_l,
               short* __restrict__ Wd_h, short* __restrict__ Wd_l)
{
    int j = blockIdx.x * 256 + threadIdx.x;   // total 2,162,688 = 8448*256
    const float* src; short *hi, *lo;
    if (j < NWQ)                { src = Wq; hi = Wq_h; lo = Wq_l; }
    else if ((j -= NWQ) < NWQ)  { src = W1; hi = W1_h; lo = W1_l; }
    else if ((j -= NWQ) < NWK)  { src = Wk; hi = Wk_h; lo = Wk_l; }
    else if ((j -= NWK) < NWK)  { src = Wv; hi = Wv_h; lo = Wv_l; }
    else                        { j -= NWK;  src = Wd; hi = Wd_h; lo = Wd_l; }
    unsigned h, l;
    split_bf16(src[j], h, l);
    hi[j] = (short)h; lo[j] = (short)l;
}

// ---------------------------------------------------------------------------
// activation pre-splits (one pass, vectorized). X: gathered vis_tok layout
// [m=b*196+n][768] so GEMM A-loads become plain row-major.
// ---------------------------------------------------------------------------
__global__ __launch_bounds__(256)
void split_x(const float* __restrict__ x, short* __restrict__ Xh,
             short* __restrict__ Xl)
{
    int idx = blockIdx.x * 256 + threadIdx.x;    // 2,408,448 chunks of 8
    int m = idx / 96, c8 = (idx - m * 96) * 8;
    int b = m / Nv_, n = m - b * Nv_;
    const float* src = x + ((size_t)(n + 1) * B_ + b) * C_ + c8;
    float av[8];
    *(float4*)&av[0] = *(const float4*)src;
    *(float4*)&av[4] = *(const float4*)(src + 4);
    uint4 Hh, Ll;
    split8_pack(av, Hh, Ll);
    *(uint4*)&Xh[(size_t)m * C_ + c8] = Hh;
    *(uint4*)&Xl[(size_t)m * C_ + c8] = Ll;
}

__global__ __launch_bounds__(256)
void split_text(const float* __restrict__ t, short* __restrict__ Th,
                short* __restrict__ Tl)
{
    int idx = blockIdx.x * 256 + threadIdx.x;    // 262,144 chunks of 8
    const float* src = t + (size_t)idx * 8;
    float av[8];
    *(float4*)&av[0] = *(const float4*)src;
    *(float4*)&av[4] = *(const float4*)(src + 4);
    uint4 Hh, Ll;
    split8_pack(av, Hh, Ll);
    *(uint4*)&Th[(size_t)idx * 8] = Hh;
    *(uint4*)&Tl[(size_t)idx * 8] = Ll;
}

// ---------------------------------------------------------------------------
// 3-term split-bf16 MFMA GEMM, all operands PRE-SPLIT in global (no VALU
// split in the k-loop — r10's 44% VALUBusy was the 6x-redundant in-loop
// split). Frag reads / MFMA order / epilogues identical to r10 ->
// bit-identical outputs. blockIdx.z==1 selects second (B,bias,C) set.
// ---------------------------------------------------------------------------
template<int EPI>
__global__ __launch_bounds__(256)
void mfma_gemm(const short* __restrict__ Ah_g, const short* __restrict__ Al_g,
               const short* __restrict__ Bh_g, const short* __restrict__ Bl_g,
               const float* __restrict__ bias,
               float* __restrict__ Cst, int Nst, int Kd,
               const float* __restrict__ W2, float* __restrict__ partials,
               const short* Bh2, const short* Bl2, const float* bias2,
               float* Cst2)
{
    if (blockIdx.z) { Bh_g = Bh2; Bl_g = Bl2; bias = bias2; Cst = Cst2; }
    __shared__ short Ah[128 * 40], Al[128 * 40], Bh[128 * 40], Bl[128 * 40];
    const int tid = threadIdx.x;
    const int m0 = blockIdx.x * 128, n0 = blockIdx.y * 128;
    const int l = tid & 63, wid = tid >> 6;
    const int wr = wid >> 1, wc = wid & 1;
    const int lr = l & 15, lq = l >> 4;

    const int srow = tid >> 2;
    const int p8 = (tid & 3) << 3;
    const short *ahp[2], *alp[2], *bhp[2], *blp[2];
    int abase[2];
#pragma unroll
    for (int i = 0; i < 2; ++i) {
        int row = srow + i * 64;
        abase[i] = row * 40 + p8;
        int gr = m0 + row;
        int gc = n0 + row;
        ahp[i] = Ah_g + (size_t)gr * Kd + p8;
        alp[i] = Al_g + (size_t)gr * Kd + p8;
        bhp[i] = Bh_g + (size_t)gc * Kd + p8;
        blp[i] = Bl_g + (size_t)gc * Kd + p8;
    }

    f32x4_t acc[4][4];
#pragma unroll
    for (int m = 0; m < 4; ++m)
#pragma unroll
        for (int n = 0; n < 4; ++n) {
            acc[m][n][0] = 0.f; acc[m][n][1] = 0.f;
            acc[m][n][2] = 0.f; acc[m][n][3] = 0.f;
        }

    for (int k0 = 0; k0 < Kd; k0 += 32) {
#pragma unroll
        for (int i = 0; i < 2; ++i) {
            *(uint4*)&Ah[abase[i]] = *(const uint4*)(ahp[i] + k0);
            *(uint4*)&Al[abase[i]] = *(const uint4*)(alp[i] + k0);
            *(uint4*)&Bh[abase[i]] = *(const uint4*)(bhp[i] + k0);
            *(uint4*)&Bl[abase[i]] = *(const uint4*)(blp[i] + k0);
        }
        __syncthreads();

        bf16x8_t ahf[4], alf[4], bhf[4], blf[4];
#pragma unroll
        for (int m = 0; m < 4; ++m) {
            int ro = (wr * 64 + m * 16 + lr) * 40 + lq * 8;
            ahf[m] = *(const bf16x8_t*)&Ah[ro];
            alf[m] = *(const bf16x8_t*)&Al[ro];
        }
#pragma unroll
        for (int n = 0; n < 4; ++n) {
            int ro = (wc * 64 + n * 16 + lr) * 40 + lq * 8;
            bhf[n] = *(const bf16x8_t*)&Bh[ro];
            blf[n] = *(const bf16x8_t*)&Bl[ro];
        }
#pragma unroll
        for (int m = 0; m < 4; ++m)
#pragma unroll
            for (int n = 0; n < 4; ++n) {
                acc[m][n] = __builtin_amdgcn_mfma_f32_16x16x32_bf16(ahf[m], bhf[n], acc[m][n], 0, 0, 0);
                acc[m][n] = __builtin_amdgcn_mfma_f32_16x16x32_bf16(ahf[m], blf[n], acc[m][n], 0, 0, 0);
                acc[m][n] = __builtin_amdgcn_mfma_f32_16x16x32_bf16(alf[m], bhf[n], acc[m][n], 0, 0, 0);
            }
        __syncthreads();
    }

    if constexpr (EPI == 0) {
#pragma unroll
        for (int n = 0; n < 4; ++n) {
            int col = n0 + wc * 64 + n * 16 + lr;
            float bv = bias ? bias[col] : 0.f;
#pragma unroll
            for (int m = 0; m < 4; ++m) {
                int rowb = m0 + wr * 64 + m * 16 + lq * 4;
#pragma unroll
                for (int r = 0; r < 4; ++r)
                    Cst[(size_t)(rowb + r) * Nst + col] = acc[m][n][r] + bv;
            }
        }
    } else {
        int coln[4]; float b1v[4], w20[4], w21[4];
#pragma unroll
        for (int n = 0; n < 4; ++n) {
            coln[n] = n0 + wc * 64 + n * 16 + lr;
            b1v[n] = bias[coln[n]];
            w20[n] = W2[coln[n]];
            w21[n] = W2[C_ + coln[n]];
        }
        const int pi = (blockIdx.y * 2 + wc) * 2;
#pragma unroll
        for (int m = 0; m < 4; ++m)
#pragma unroll
            for (int r = 0; r < 4; ++r) {
                float p0 = 0.f, p1 = 0.f;
#pragma unroll
                for (int n = 0; n < 4; ++n) {
                    float h = acc[m][n][r] + b1v[n];
                    float gl = h / (1.f + expf(-1.702f * h));
                    p0 = fmaf(gl, w20[n], p0);
                    p1 = fmaf(gl, w21[n], p1);
                }
#pragma unroll
                for (int off = 8; off; off >>= 1) {
                    p0 += __shfl_xor(p0, off, 16);
                    p1 += __shfl_xor(p1, off, 16);
                }
                if (lr == 0) {
                    int row = m0 + wr * 64 + m * 16 + lq * 4 + r;
                    partials[(size_t)row * 24 + pi + 0] = p0;
                    partials[(size_t)row * 24 + pi + 1] = p1;
                }
            }
    }
}

// ---------------------------------------------------------------------------
// fp32 NT GEMM (batched gram only). r5-verified.
// ---------------------------------------------------------------------------
template<int GATHER_A, int BOUNDS, int EPI>
__global__ __launch_bounds__(256)
void gemm_nt(const float* __restrict__ A, const float* __restrict__ Bm,
             const float* __restrict__ bias, float* __restrict__ C,
             int M, int N, int K, float scale,
             long strideA, long strideC,
             const float* __restrict__ W2, float* __restrict__ partials)
{
    __shared__ float As[16][132];
    __shared__ float Bs[16][132];
    const int tid = threadIdx.x;
    const int tx = tid & 15, ty = tid >> 4;
    const int m0 = blockIdx.x * 128, n0 = blockIdx.y * 128;
    const int bz = blockIdx.z;
    const float* Ab = A  + (size_t)bz * strideA;
    const float* Bb = Bm + (size_t)bz * strideA;
    float* Cb = C + (size_t)bz * strideC;

    const int lrow = tid >> 2;
    const int lk   = (tid & 3) << 2;

    const float* aptr[2]; const float* bptr[2];
    bool aval[2], bval[2];
#pragma unroll
    for (int Lq = 0; Lq < 2; ++Lq) {
        int row = lrow + Lq * 64;
        int gr = m0 + row;
        aval[Lq] = (!BOUNDS) || (gr < M);
        aptr[Lq] = Ab + (size_t)(aval[Lq] ? gr : 0) * K + lk;
        int gc = n0 + row;
        bval[Lq] = (!BOUNDS) || (gc < N);
        bptr[Lq] = Bb + (size_t)(bval[Lq] ? gc : 0) * K + lk;
    }

    float acc[8][8];
#pragma unroll
    for (int r = 0; r < 8; ++r)
#pragma unroll
        for (int c = 0; c < 8; ++c) acc[r][c] = 0.f;

    for (int k0 = 0; k0 < K; k0 += 16) {
#pragma unroll
        for (int Lq = 0; Lq < 2; ++Lq) {
            int row = lrow + Lq * 64;
            float4 va = aval[Lq] ? *(const float4*)(aptr[Lq] + k0)
                                 : make_float4(0.f, 0.f, 0.f, 0.f);
            As[lk+0][row] = va.x; As[lk+1][row] = va.y;
            As[lk+2][row] = va.z; As[lk+3][row] = va.w;
            float4 vb = bval[Lq] ? *(const float4*)(bptr[Lq] + k0)
                                 : make_float4(0.f, 0.f, 0.f, 0.f);
            Bs[lk+0][row] = vb.x; Bs[lk+1][row] = vb.y;
            Bs[lk+2][row] = vb.z; Bs[lk+3][row] = vb.w;
        }
        __syncthreads();
#pragma unroll
        for (int kk = 0; kk < 16; ++kk) {
            float a[8], bfr[8];
            *(float4*)&a[0]   = *(const float4*)&As[kk][ty * 8];
            *(float4*)&a[4]   = *(const float4*)&As[kk][ty * 8 + 4];
            *(float4*)&bfr[0] = *(const float4*)&Bs[kk][tx * 4];
            *(float4*)&bfr[4] = *(const float4*)&Bs[kk][64 + tx * 4];
#pragma unroll
            for (int r = 0; r < 8; ++r)
#pragma unroll
                for (int c = 0; c < 8; ++c)
                    acc[r][c] = fmaf(a[r], bfr[c], acc[r][c]);
        }
        __syncthreads();
    }

#pragma unroll
    for (int r = 0; r < 8; ++r) {
        int gr = m0 + ty * 8 + r;
        if (BOUNDS && gr >= M) continue;
#pragma unroll
        for (int half = 0; half < 2; ++half) {
            int gc = n0 + half * 64 + tx * 4;
#pragma unroll
            for (int c = 0; c < 4; ++c) {
                if (!BOUNDS || gc + c < N) {
                    float v = acc[r][half*4+c] * scale;
                    if (bias) v += bias[gc+c];
                    Cb[(size_t)gr * N + gc + c] = v;
                }
            }
        }
    }
}

// ---------------------------------------------------------------------------
// Attention per (b,h) — r10-verified structure (4 rows/wave, all-lane score,
// prefetch). CHANGE: output written as pre-split hi/lo bf16 (Fh/Fl) via the
// SAME split_bf16 the MLP GEMM previously applied in-kernel -> MLP MFMA
// inputs bit-identical. q buffer no longer written (G overlay safe).
// ---------------------------------------------------------------------------
__global__ __launch_bounds__(256)
void attn_kernel(const float* __restrict__ q, const float* __restrict__ k,
                 const float* __restrict__ v, const float* __restrict__ x,
                 short* __restrict__ Fh, short* __restrict__ Fl)
{
    __shared__ float Ks[Lt_][DH_ + 4];
    __shared__ float Vs[Lt_][DH_ + 1];
    __shared__ float qs[16][DH_];
    __shared__ float as[16][Lt_];
    const int bh = blockIdx.x;
    const int b = bh / H_, h = bh - b * H_;
    const int tid = threadIdx.x;
    const int wv = tid >> 6, lane = tid & 63;
    const int half = lane >> 5;
    const int key = lane & 31;

    for (int idx = tid; idx < Lt_ * 16; idx += 256) {
        int l = idx >> 4, dq = (idx & 15) << 2;
        size_t off = ((size_t)(b * Lt_ + l)) * C_ + h * DH_ + dq;
        float4 kv4 = *(const float4*)(k + off);
        Ks[l][dq] = kv4.x; Ks[l][dq + 1] = kv4.y; Ks[l][dq + 2] = kv4.z; Ks[l][dq + 3] = kv4.w;
        float4 vv4 = *(const float4*)(v + off);
        Vs[l][dq] = vv4.x; Vs[l][dq + 1] = vv4.y; Vs[l][dq + 2] = vv4.z; Vs[l][dq + 3] = vv4.w;
    }
    __syncthreads();

    const size_t qbase = (size_t)b * Nv_ * C_ + h * DH_ + lane;
    const size_t xbase = (size_t)b * C_ + h * DH_ + lane;

    float qv[4], xv[4];
#pragma unroll
    for (int j = 0; j < 4; ++j) {
        qv[j] = q[qbase + (size_t)(wv * 4 + j) * C_];
        xv[j] = x[xbase + (size_t)(wv * 4 + j + 1) * B_ * C_];
    }

    for (int it = 0; it < 13; ++it) {
        const int base = it * 16 + wv * 4;
        if (base > 192) break;
        float cq[4], cx[4];
#pragma unroll
        for (int j = 0; j < 4; ++j) { cq[j] = qv[j]; cx[j] = xv[j]; }
        const int nbase = base + 16;
        if (nbase <= 192) {
#pragma unroll
            for (int j = 0; j < 4; ++j) {
                qv[j] = q[qbase + (size_t)(nbase + j) * C_];
                xv[j] = x[xbase + (size_t)(nbase + j + 1) * B_ * C_];
            }
        }
        const int ws = wv * 4;
#pragma unroll
        for (int j = 0; j < 4; ++j) qs[ws + j][lane] = cq[j];

        const int s0 = ws + half * 2;
        float s1 = 0.f, s2 = 0.f;
#pragma unroll
        for (int d4 = 0; d4 < DH_; d4 += 4) {
            float4 k4  = *(const float4*)&Ks[key][d4];
            float4 q4a = *(const float4*)&qs[s0][d4];
            float4 q4b = *(const float4*)&qs[s0 + 1][d4];
            s1 = fmaf(q4a.x, k4.x, s1); s2 = fmaf(q4b.x, k4.x, s2);
            s1 = fmaf(q4a.y, k4.y, s1); s2 = fmaf(q4b.y, k4.y, s2);
            s1 = fmaf(q4a.z, k4.z, s1); s2 = fmaf(q4b.z, k4.z, s2);
            s1 = fmaf(q4a.w, k4.w, s1); s2 = fmaf(q4b.w, k4.w, s2);
        }
        s1 *= 0.125f; s2 *= 0.125f;
        float mx1 = s1, mx2 = s2;
#pragma unroll
        for (int off = 16; off; off >>= 1) {
            mx1 = fmaxf(mx1, __shfl_xor(mx1, off, 32));
            mx2 = fmaxf(mx2, __shfl_xor(mx2, off, 32));
        }
        float p1v = expf(s1 - mx1);
        float p2v = expf(s2 - mx2);
        float su1 = p1v, su2 = p2v;
#pragma unroll
        for (int off = 16; off; off >>= 1) {
            su1 += __shfl_xor(su1, off, 32);
            su2 += __shfl_xor(su2, off, 32);
        }
        as[s0][key] = p1v / su1;
        as[s0 + 1][key] = p2v / su2;

        float c0 = 0.f, c1 = 0.f, c2 = 0.f, c3 = 0.f;
#pragma unroll
        for (int l4 = 0; l4 < Lt_; l4 += 4) {
            float4 a0 = *(const float4*)&as[ws + 0][l4];
            float4 a1 = *(const float4*)&as[ws + 1][l4];
            float4 a2 = *(const float4*)&as[ws + 2][l4];
            float4 a3 = *(const float4*)&as[ws + 3][l4];
            float v0 = Vs[l4 + 0][lane], v1 = Vs[l4 + 1][lane];
            float v2 = Vs[l4 + 2][lane], v3 = Vs[l4 + 3][lane];
            c0 = fmaf(a0.x, v0, c0); c1 = fmaf(a1.x, v0, c1);
            c2 = fmaf(a2.x, v0, c2); c3 = fmaf(a3.x, v0, c3);
            c0 = fmaf(a0.y, v1, c0); c1 = fmaf(a1.y, v1, c1);
            c2 = fmaf(a2.y, v1, c2); c3 = fmaf(a3.y, v1, c3);
            c0 = fmaf(a0.z, v2, c0); c1 = fmaf(a1.z, v2, c1);
            c2 = fmaf(a2.z, v2, c2); c3 = fmaf(a3.z, v2, c3);
            c0 = fmaf(a0.w, v3, c0); c1 = fmaf(a1.w, v3, c1);
            c2 = fmaf(a2.w, v3, c2); c3 = fmaf(a3.w, v3, c3);
        }
        float fo[4] = {c0 + cx[0], c1 + cx[1], c2 + cx[2], c3 + cx[3]};
#pragma unroll
        for (int j = 0; j < 4; ++j) {
            unsigned hh, ll;
            split_bf16(fo[j], hh, ll);
            Fh[qbase + (size_t)(base + j) * C_] = (short)hh;
            Fl[qbase + (size_t)(base + j) * C_] = (short)ll;
        }
    }
}

// ---------------------------------------------------------------------------
// keep decisions: logits from partials[m][24] (+b2), gumbel, policy, keep_prob
// ---------------------------------------------------------------------------
__global__ __launch_bounds__(256)
void keep_kernel(const float* __restrict__ partials, const float* __restrict__ b2,
                 const float* __restrict__ gumbel, float* __restrict__ policy,
                 float* __restrict__ keep_prob)
{
    int m = blockIdx.x * 256 + threadIdx.x;
    int b = m / Nv_, n = m - b * Nv_;
    float l0 = b2[0], l1 = b2[1];
#pragma unroll
    for (int t = 0; t < 12; ++t) {
        l0 += partials[(size_t)m * 24 + t * 2 + 0];
        l1 += partials[(size_t)m * 24 + t * 2 + 1];
    }
    const float UHI = (float)(1.0 - 1e-6);
    float U0 = fminf(fmaxf(gumbel[(size_t)m * 2 + 0], 1e-6f), UHI);
    float U1 = fminf(fmaxf(gumbel[(size_t)m * 2 + 1], 1e-6f), UHI);
    float t0 = (float)log((double)U0);
    float g0 = -(float)log((double)(-t0));
    float t1 = (float)log((double)U1);
    float g1 = -(float)log((double)(-t1));
    float dlog = (l1 + g1) - (l0 + g0);
    float kp = 1.f / (1.f + expf(-dlog));
    policy[(size_t)b * 197 + 1 + n] = (dlog > 0.f) ? 1.f : 0.f;
    if (n == 0) policy[(size_t)b * 197] = 1.f;
    keep_prob[m] = kp;
}

__global__ __launch_bounds__(256)
void batch_reduce(const float* __restrict__ keep_prob, float* __restrict__ sum_kp)
{
    __shared__ float part[4];
    int b = blockIdx.x, tid = threadIdx.x;
    float vs = (tid < Nv_) ? keep_prob[(size_t)b * Nv_ + tid] : 0.f;
#pragma unroll
    for (int off = 32; off; off >>= 1) vs += __shfl_xor(vs, off, 64);
    if ((tid & 63) == 0) part[tid >> 6] = vs;
    __syncthreads();
    if (tid == 0) sum_kp[b] = part[0] + part[1] + part[2] + part[3];
}

__global__ __launch_bounds__(256)
void pw_scale(float* __restrict__ phi, const float* __restrict__ keep_prob,
              const float* __restrict__ sum_kp)
{
    int m = blockIdx.x * 4 + (threadIdx.x >> 6);
    int lane = threadIdx.x & 63;
    float4* row = (float4*)phi + (size_t)m * 64;
    float4 vv = row[lane];
    float ss = vv.x * vv.x + vv.y * vv.y + vv.z * vv.z + vv.w * vv.w;
#pragma unroll
    for (int off = 32; off; off >>= 1) ss += __shfl_xor(ss, off, 64);
    float nrm = fmaxf(sqrtf(ss), 1e-12f);
    int b = m / Nv_;
    float kp = keep_prob[m];
    float meanw = sum_kp[b] * (1.f / 196.f);
    float wn = fmaxf(kp / (meanw + 1e-12f), 1e-6f);
    float sc = sqrtf(wn) / nrm;
    vv.x *= sc; vv.y *= sc; vv.z *= sc; vv.w *= sc;
    row[lane] = vv;
}

// ---------------------------------------------------------------------------
// Per-batch blocked Cholesky logdet, panel-in-registers (r8-verified).
// ---------------------------------------------------------------------------
#define LS_   197
#define PBS_  14

__global__ __launch_bounds__(256)
void chol_kernel(const float* __restrict__ G, float* __restrict__ logdet_arr)
{
    extern __shared__ float sm[];
    float* Am  = sm;                          // 196 * 197
    float (*colraw)[PBS_] = (float(*)[PBS_])(sm + 196 * LS_);
    const int b = blockIdx.x, tid = threadIdx.x;
    const float* Gb = G + (size_t)b * Nv_ * Nv_;

    for (int idx = tid; idx < Nv_ * 49; idx += 256) {
        int i = idx / 49, c4 = (idx - i * 49) * 4;
        float4 v = *(const float4*)(Gb + (size_t)i * Nv_ + c4);
        if (i >= c4 && i < c4 + 4) (&v.x)[i - c4] += 1.00001f;
        float* dst = Am + i * LS_ + c4;
        dst[0] = v.x; dst[1] = v.y; dst[2] = v.z; dst[3] = v.w;
    }
    __syncthreads();

    float acc = 0.f;
    const int tx = tid & 15, ty = tid >> 4;

    for (int p = 0; p < Nv_ / PBS_; ++p) {
        const int j0 = p * PBS_;
        const int j1 = j0 + PBS_;
        const int i = tid;
        const bool haveRow = (i >= j0 && i < Nv_);

        float Rp[PBS_];
        if (haveRow) {
#pragma unroll
            for (int t = 0; t < PBS_; ++t) Rp[t] = Am[i * LS_ + j0 + t];
            if (i < j1) colraw[0][i - j0] = Rp[0];
        }

        for (int jj = 0; jj < PBS_; ++jj) {
            __syncthreads();
            const int j = j0 + jj;
            float piv = colraw[jj][jj];
            if (tid == 0) acc += logf(piv);
            float inv = 1.f / sqrtf(piv);
            if (haveRow && i >= j) {
                float lij = Rp[jj] * inv;
                Rp[jj] = lij;
#pragma unroll
                for (int k = 0; k < PBS_; ++k) {
                    if (k > jj) {
                        float lk = colraw[jj][k] * inv;
                        Rp[k] = fmaf(-lij, lk, Rp[k]);
                    }
                }
                if (jj < PBS_ - 1 && i > j && i < j1)
                    colraw[jj + 1][i - j0] = Rp[jj + 1];
            }
        }

        if (haveRow) {
#pragma unroll
            for (int t = 0; t < PBS_; ++t) Am[i * LS_ + j0 + t] = Rp[t];
        }
        __syncthreads();

        if (j1 >= Nv_) break;
        const int s = Nv_ - j1;
        const int nb = (s + 63) >> 6;
        for (int rb = 0; rb < nb; ++rb) {
            const int i0 = j1 + rb * 64;
            float Li[4][PBS_];
#pragma unroll
            for (int r = 0; r < 4; ++r) {
                int ir = i0 + ty + 16 * r; if (ir > 195) ir = 195;
#pragma unroll
                for (int t = 0; t < PBS_; ++t) Li[r][t] = Am[ir * LS_ + j0 + t];
            }
            for (int cb = 0; cb <= rb; ++cb) {
                const int k0 = j1 + cb * 64;
                float accs[4][4];
#pragma unroll
                for (int r = 0; r < 4; ++r)
#pragma unroll
                    for (int c = 0; c < 4; ++c) accs[r][c] = 0.f;
#pragma unroll
                for (int t = 0; t < PBS_; ++t) {
                    float Lk[4];
#pragma unroll
                    for (int c = 0; c < 4; ++c) {
                        int kx = k0 + 4 * tx + c; if (kx > 195) kx = 195;
                        Lk[c] = Am[kx * LS_ + j0 + t];
                    }
#pragma unroll
                    for (int r = 0; r < 4; ++r)
#pragma unroll
                        for (int c = 0; c < 4; ++c)
                            accs[r][c] = fmaf(Li[r][t], Lk[c], accs[r][c]);
                }
#pragma unroll
                for (int r = 0; r < 4; ++r) {
                    int ir = i0 + ty + 16 * r;
                    if (ir < Nv_) {
#pragma unroll
                        for (int c = 0; c < 4; ++c) {
                            int kx = k0 + 4 * tx + c;
                            if (kx < Nv_) Am[ir * LS_ + kx] -= accs[r][c];
                        }
                    }
                }
            }
        }
        __syncthreads();
    }
    if (tid == 0) logdet_arr[b] = acc;
}

__global__ void finalize_kernel(const float* __restrict__ sum_kp,
                                const float* __restrict__ logdet_arr,
                                float* __restrict__ out)
{
    float tot = 0.f, ld = 0.f;
    for (int b = 0; b < B_; ++b) { tot += sum_kp[b]; ld += logdet_arr[b]; }
    float mean = tot * (1.f / 25088.f);
    float d = mean - 0.7f;
    out[25216] = d * d;
    out[25217] = -ld * (1.f / 128.f);
}

// ---------------------------------------------------------------------------
extern "C" void kernel_launch(void* const* d_in, const int* in_sizes, int n_in,
                              void* d_out, int out_size, void* d_ws, size_t ws_size,
                              hipStream_t stream)
{
    const float* x      = (const float*)d_in[0];
    const float* text   = (const float*)d_in[1];
    const float* gumbel = (const float*)d_in[2];
    const float* Wq     = (const float*)d_in[3];
    const float* bq     = (const float*)d_in[4];
    const float* Wk     = (const float*)d_in[5];
    const float* bk     = (const float*)d_in[6];
    const float* Wv     = (const float*)d_in[7];
    const float* bv     = (const float*)d_in[8];
    const float* W1     = (const float*)d_in[9];
    const float* b1     = (const float*)d_in[10];
    const float* W2     = (const float*)d_in[11];
    const float* b2     = (const float*)d_in[12];
    const float* Wdpp   = (const float*)d_in[13];
    float* out = (float*)d_out;

    float* ws = (float*)d_ws;
    float* q          = ws;                       // 19,267,584 f ; G overlays
    float* kbuf       = q + 19267584;             //  3,145,728
    float* vbuf       = kbuf + 3145728;           //  3,145,728
    float* phi        = vbuf + 3145728;           //  6,422,528
    float* partials   = phi + 6422528;            //    602,112
    float* keep_prob  = partials + 602112;        //     25,088
    float* sum_kp     = keep_prob + 25088;        //        128
    float* logdet_arr = sum_kp + 128;             //        128
    float* G          = ws;                       // reuse q (dead after attn)

    short* Wq_h = (short*)(logdet_arr + 128);     // weight splits (r9 layout)
    short* Wq_l = Wq_h + 589824;
    short* W1_h = Wq_l + 589824;
    short* W1_l = W1_h + 589824;
    short* Wk_h = W1_l + 589824;
    short* Wk_l = Wk_h + 393216;
    short* Wv_h = Wk_l + 393216;
    short* Wv_l = Wv_h + 393216;
    short* Wd_h = Wv_l + 393216;
    short* Wd_l = Wd_h + 196608;
    // activation splits
    short* Xh = Wd_l + 196608;                    // 19,267,584 shorts each
    short* Xl = Xh + 19267584;
    short* Th = Xl + 19267584;                    //  2,097,152 shorts each
    short* Tl = Th + 2097152;
    short* Fh = Xh;                               // overlay: X dead after phi
    short* Fl = Xl;

    dim3 blk(256);

    split_all<<<dim3(8448), blk, 0, stream>>>(Wq, W1, Wk, Wv, Wdpp,
                                              Wq_h, Wq_l, W1_h, W1_l,
                                              Wk_h, Wk_l, Wv_h, Wv_l,
                                              Wd_h, Wd_l);
    split_x<<<dim3(9408), blk, 0, stream>>>(x, Xh, Xl);
    split_text<<<dim3(1024), blk, 0, stream>>>(text, Th, Tl);

    // k+v projections merged (z=0 -> k, z=1 -> v): M=4096, N=768, K=512
    mfma_gemm<0><<<dim3(32,6,2), blk, 0, stream>>>(Th, Tl, Wk_h, Wk_l, bk, kbuf, 768, 512,
                                                   nullptr, nullptr,
                                                   Wv_h, Wv_l, bv, vbuf);
    // q projection: M=25088, N=768, K=768
    mfma_gemm<0><<<dim3(196,6,1), blk, 0, stream>>>(Xh, Xl, Wq_h, Wq_l, bq, q, 768, 768,
                                                    nullptr, nullptr,
                                                    Wq_h, Wq_l, bq, q);
    // phi projection (BEFORE attn: X region is reused as F after): N=256
    mfma_gemm<0><<<dim3(196,2,1), blk, 0, stream>>>(Xh, Xl, Wd_h, Wd_l, nullptr, phi, 256, 768,
                                                    nullptr, nullptr,
                                                    Wd_h, Wd_l, nullptr, phi);
    // attention -> pre-split fused (Fh/Fl over X region)
    attn_kernel<<<dim3(B_*H_), blk, 0, stream>>>(q, kbuf, vbuf, x, Fh, Fl);
    // MLP with gelu/W2 epilogue
    mfma_gemm<1><<<dim3(196,6,1), blk, 0, stream>>>(Fh, Fl, W1_h, W1_l, b1, nullptr, 768, 768,
                                                    W2, partials,
                                                    W1_h, W1_l, b1, nullptr);
    keep_kernel<<<dim3(98), blk, 0, stream>>>(partials, b2, gumbel, out, keep_prob);
    batch_reduce<<<dim3(B_), blk, 0, stream>>>(keep_prob, sum_kp);
    pw_scale<<<dim3(6272), blk, 0, stream>>>(phi, keep_prob, sum_kp);
    gemm_nt<0,1,0><<<dim3(2,2,B_), blk, 0, stream>>>(phi, phi, nullptr, G, Nv_, Nv_, 256,
                                                     1.0f/(256.0f*196.0f*0.01f),
                                                     (long)Nv_*256, (long)Nv_*Nv_, nullptr, nullptr);
    size_t shb = (size_t)(Nv_ * LS_ + Nv_) * sizeof(float);
    (void)hipFuncSetAttribute((const void*)chol_kernel,
                              hipFuncAttributeMaxDynamicSharedMemorySize, (int)shb);
    chol_kernel<<<dim3(B_), blk, shb, stream>>>(G, logdet_arr);
    finalize_kernel<<<dim3(1), dim3(1), 0, stream>>>(sum_kp, logdet_arr, out);
}